// Round 12
// baseline (275.387 us; speedup 1.0000x reference)
//
#include <hip/hip_runtime.h>
#include <stdint.h>

#define MDIM 16384
#define NDIM 1020
#define KDIM 2048
#define NPAD 1024
#define TK   (KDIM / 64)   // 32 K-tiles of BK=64

typedef __attribute__((ext_vector_type(4))) float f32x4;
typedef __attribute__((ext_vector_type(8))) short short8;

#define MFMA16(a, b, c) __builtin_amdgcn_mfma_f32_16x16x32_bf16((a), (b), (c), 0, 0, 0)

// asm ds_read_b128 / ds_write_b64, register-only constraints; completion via
// manual lgkmcnt (+ sched_barrier(0) per rule 18).
template <int OFF>
static __device__ __forceinline__ short8 dsr(unsigned addr) {
    short8 r;
    asm volatile("ds_read_b128 %0, %1 offset:%2" : "=v"(r) : "v"(addr), "i"(OFF));
    return r;
}
template <int OFF>
static __device__ __forceinline__ void dsw64(unsigned addr, uint2 v) {
    asm volatile("ds_write_b64 %0, %1 offset:%2" :: "v"(addr), "v"(v), "i"(OFF));
}

// f32 -> bf16 round-to-nearest (half-up) + pack two into one u32.
__device__ __forceinline__ unsigned packbf(float lo, float hi) {
    const unsigned r0 = __float_as_uint(lo) + 0x8000u;
    const unsigned r1 = __float_as_uint(hi) + 0x8000u;
    return __builtin_amdgcn_perm(r1, r0, 0x07060302u);
}

// f32 -> bf16 RNE (prep kernels)
__device__ __forceinline__ unsigned short f2bf(float f) {
    unsigned int u = __float_as_uint(f);
    unsigned int r = (u + 0x7FFFu + ((u >> 16) & 1u)) >> 16;
    return (unsigned short)r;
}

// ---------------------------------------------------------------------------
// Kernel 1: W [K=2048][N=1020] f32 -> Wt [NPAD=1024][K=2048] bf16 (transposed)
// rows 1020..1023 zeroed.
// ---------------------------------------------------------------------------
__global__ void prep_w_kernel(const float* __restrict__ W,
                              unsigned short* __restrict__ Wt) {
    const int id = blockIdx.x * 256 + threadIdx.x;  // 512 blocks * 256
    const int n0 = (id & 255) * 4;
    const int k0 = (id >> 8) * 4;
    float a[4][4];
    if (n0 < NDIM) {
#pragma unroll
        for (int i = 0; i < 4; ++i) {
            const float* p = W + (size_t)(k0 + i) * NDIM + n0;
            a[i][0] = p[0]; a[i][1] = p[1]; a[i][2] = p[2]; a[i][3] = p[3];
        }
    } else {
#pragma unroll
        for (int i = 0; i < 4; ++i)
#pragma unroll
            for (int j = 0; j < 4; ++j) a[i][j] = 0.f;
    }
#pragma unroll
    for (int j = 0; j < 4; ++j) {
        uint2 p;
        p.x = (unsigned)f2bf(a[0][j]) | ((unsigned)f2bf(a[1][j]) << 16);
        p.y = (unsigned)f2bf(a[2][j]) | ((unsigned)f2bf(a[3][j]) << 16);
        *(uint2*)(Wt + (size_t)(n0 + j) * KDIM + k0) = p;
    }
}

// ---------------------------------------------------------------------------
// Kernel 1b (FALLBACK PATH ONLY): x f32 -> Xb bf16
// ---------------------------------------------------------------------------
__global__ void prep_x_kernel(const float* __restrict__ x,
                              unsigned short* __restrict__ Xb) {
    const size_t total = (size_t)MDIM * KDIM;
    const size_t stride = (size_t)gridDim.x * 256 * 8;
    for (size_t i = ((size_t)blockIdx.x * 256 + threadIdx.x) * 8; i < total; i += stride) {
        const float4 v0 = *(const float4*)(x + i);
        const float4 v1 = *(const float4*)(x + i + 4);
        uint4 p;
        p.x = (unsigned)f2bf(v0.x) | ((unsigned)f2bf(v0.y) << 16);
        p.y = (unsigned)f2bf(v0.z) | ((unsigned)f2bf(v0.w) << 16);
        p.z = (unsigned)f2bf(v1.x) | ((unsigned)f2bf(v1.y) << 16);
        p.w = (unsigned)f2bf(v1.z) | ((unsigned)f2bf(v1.w) << 16);
        *(uint4*)(Xb + i) = p;
    }
}

// ---------------------------------------------------------------------------
// Kernel 2 (R12): fused GEMM + ACTIVATION. 256(M) x 255(N: 5 spans) tile,
// BK=64, 8 waves. Main loop = R11 (fused f32->bf16 A staging) with col base
// bn*255. Epilogue: write outputs, then per 128-row half: dump acc+bias ->
// LDS f32[128][256], __syncthreads, each wave does 16 rows x 5 spans of
// {tanh | gumbel-softmax} (same math as the verified act kernel), writes dt.
// Span-aligned tiles mean every softmax span is block-local. Col 255 of each
// tile duplicates the neighbor's col 0 (identical value, benign); global col
// 1020 (bn=3) masked. u/dt accesses are 204B-contiguous per (row,span).
// ---------------------------------------------------------------------------
extern "C" __global__ __launch_bounds__(512, 1) void gemm12_kernel(
    const float* __restrict__ x,
    const unsigned short* __restrict__ Wt,
    const float* __restrict__ bias,
    const float* __restrict__ u,
    float* __restrict__ out,
    float* __restrict__ dt) {
    extern __shared__ unsigned short lds_raw[];  // 128 KiB

    const int tid  = threadIdx.x;
    const int lane = tid & 63;
    const int wid  = tid >> 6;   // 0..7
    const int wr   = wid >> 2;   // 0..1 (M)
    const int wc   = wid & 3;    // 0..3 (N)

    // XCD-aware swizzle: 256 blocks, 8 XCDs, 32 consecutive per XCD.
    const int bid = blockIdx.x;
    const int swz = (bid & 7) * 32 + (bid >> 3);
    const int bm  = swz >> 2;    // 0..63
    const int bn  = swz & 3;     // 0..3  (col base bn*255)

    // B staging source (rule 21 pre-swizzle); rows bn*255 .. bn*255+255
    const int srow = bn * 255 + wid * 8 + (lane >> 3);
    const int scb  = ((lane & 7) ^ (lane >> 3)) * 8;
    const unsigned short* bS = Wt + (size_t)srow * KDIM + scb;

#define STAGEB(BUFI, STRIPE, S) do {                                             \
    const unsigned short* sp_ =                                                  \
        bS + (size_t)((STRIPE) * 64) * KDIM + (size_t)(((S) & 31) * 64);         \
    __builtin_amdgcn_global_load_lds(                                            \
        (const __attribute__((address_space(1))) unsigned int*)sp_,              \
        (__attribute__((address_space(3))) unsigned int*)(lds_raw +              \
            (BUFI) * 32768 + 16384 + ((STRIPE) * 64 + wid * 8) * 64),            \
        16, 0, 0);                                                               \
} while (0)

    // A direct-f32 source: lane covers row r = wid*32 + i*4 + h (i=0..7),
    // k-group g = lane&15 (float4 at k=g*4) -- fully coalesced.
    const int h = lane >> 4, g = lane & 15;
    const float* aF = x + (size_t)(bm * 256 + wid * 32 + h) * KDIM + g * 4;

    // A LDS write: byte = buf*65536 + r*128 + ((g>>1 ^ (r&7))<<4) + (g&1)*8
    // r&7 = 4*(i&1)+h -> base E (i even); O = E ^ 0x40 (XOR! R9's carry bug).
    const unsigned ldsbase =
        (unsigned)(uintptr_t)(__attribute__((address_space(3))) unsigned short*)lds_raw;
    const unsigned awbE =
        ldsbase + (unsigned)(wid * 32 + h) * 128 +
        ((unsigned)((g >> 1) ^ h) << 4) + (unsigned)(g & 1) * 8;
    const unsigned awbO  = awbE ^ 0x40u;
    const unsigned awb0E = awbE,           awb0O = awbO;
    const unsigned awb1E = awbE + 65536u,  awb1O = awbO + 65536u;

    float4 av[8];
#define AGLD(T) {                                                     \
    const float* ap_ = aF + (size_t)(((T) & 31) * 64);                \
    av[0] = *(const float4*)(ap_);                                    \
    av[1] = *(const float4*)(ap_ + 4 * KDIM);                         \
    av[2] = *(const float4*)(ap_ + 8 * KDIM);                         \
    av[3] = *(const float4*)(ap_ + 12 * KDIM);                        \
    av[4] = *(const float4*)(ap_ + 16 * KDIM);                        \
    av[5] = *(const float4*)(ap_ + 20 * KDIM);                        \
    av[6] = *(const float4*)(ap_ + 24 * KDIM);                        \
    av[7] = *(const float4*)(ap_ + 28 * KDIM);                        \
}
#define CVT1(AWE, AWO, I)                                             \
    { uint2 v_;                                                       \
      v_.x = packbf(av[I].x, av[I].y);                                \
      v_.y = packbf(av[I].z, av[I].w);                                \
      dsw64<(I) * 512>(((I) & 1) ? (AWO) : (AWE), v_); }
#define CVTW(AWE, AWO)                                                \
    CVT1(AWE, AWO, 0) CVT1(AWE, AWO, 1) CVT1(AWE, AWO, 2)             \
    CVT1(AWE, AWO, 3) CVT1(AWE, AWO, 4) CVT1(AWE, AWO, 5)             \
    CVT1(AWE, AWO, 6) CVT1(AWE, AWO, 7)

    // A/B LDS read addressing (verified R3/R4)
    const unsigned l15 = lane & 15, hi = lane >> 4, l7 = lane & 7;
    const unsigned c0 = (unsigned)((0 * 4 + hi) ^ l7) << 4;
    const unsigned c1 = (unsigned)((1 * 4 + hi) ^ l7) << 4;
    const unsigned pbA = ldsbase + (unsigned)(wr * 128 + l15) * 128;
    const unsigned pbB = ldsbase + 32768u + (unsigned)(wc * 64 + l15) * 128;
    const unsigned aA0_0 = pbA + c0,          aA0_1 = pbA + c1;
    const unsigned aA1_0 = pbA + 65536u + c0, aA1_1 = pbA + 65536u + c1;
    const unsigned bB0_0 = pbB + c0,          bB0_1 = pbB + c1;
    const unsigned bB1_0 = pbB + 65536u + c0, bB1_1 = pbB + 65536u + c1;

    f32x4 acc[8][4];
#pragma unroll
    for (int i = 0; i < 8; ++i)
#pragma unroll
        for (int j = 0; j < 4; ++j) {
            f32x4 z = {0.f, 0.f, 0.f, 0.f};
            acc[i][j] = z;
        }

#define PH_TAIL                                                       \
    __builtin_amdgcn_s_barrier();                                     \
    asm volatile("s_waitcnt lgkmcnt(0)" ::: "memory");                \
    __builtin_amdgcn_sched_barrier(0);                                \
    __builtin_amdgcn_s_setprio(1);

// k2-outer: 8 independent MFMAs, then 8 more; same-acc dep distance 8.
#define PH_MFMA(MF0)                                                  \
    _Pragma("unroll")                                                 \
    for (int k2 = 0; k2 < 2; ++k2)                                    \
        _Pragma("unroll")                                             \
        for (int nf = 0; nf < 4; ++nf) {                              \
            acc[MF0][nf]     = MFMA16(af0[k2], bfv[nf][k2], acc[MF0][nf]);     \
            acc[MF0 + 1][nf] = MFMA16(af1[k2], bfv[nf][k2], acc[MF0 + 1][nf]); \
        }                                                             \
    __builtin_amdgcn_s_setprio(0);

#define RDA(BUF, MF0)                                                 \
    af0[0] = dsr<(MF0) * 2048>(aA##BUF##_0);                          \
    af0[1] = dsr<(MF0) * 2048>(aA##BUF##_1);                          \
    af1[0] = dsr<(MF0) * 2048 + 2048>(aA##BUF##_0);                   \
    af1[1] = dsr<(MF0) * 2048 + 2048>(aA##BUF##_1);

#define RDB(BUF, NF)                                                  \
    bfv[NF][0] = dsr<(NF) * 2048>(bB##BUF##_0);                       \
    bfv[NF][1] = dsr<(NF) * 2048>(bB##BUF##_1);

#define TILE(T, BUF, NB, AWE, AWO)                                              \
  {                                                                             \
    short8 bfv[4][2];                                                           \
    short8 af0[2], af1[2];                                                      \
    /* p0: reads B(t)+A(t)mf01; issue 8 av gloads (t+1) */                      \
    RDB(BUF, 0) RDB(BUF, 1) RDB(BUF, 2) RDB(BUF, 3)                             \
    RDA(BUF, 0)                                                                 \
    AGLD((T) + 1)                                                               \
    PH_TAIL                                                                     \
    PH_MFMA(0)                                                                  \
    __builtin_amdgcn_s_barrier();                                               \
    /* p1: stage B(t+2) first half -> BUF */                                    \
    RDA(BUF, 2)                                                                 \
    STAGEB(BUF, 0, (T) + 2); STAGEB(BUF, 1, (T) + 2);                           \
    PH_TAIL                                                                     \
    PH_MFMA(2)                                                                  \
    __builtin_amdgcn_s_barrier();                                               \
    /* p2: stage B(t+2) second half -> BUF */                                   \
    RDA(BUF, 4)                                                                 \
    STAGEB(BUF, 2, (T) + 2); STAGEB(BUF, 3, (T) + 2);                           \
    PH_TAIL                                                                     \
    PH_MFMA(4)                                                                  \
    __builtin_amdgcn_s_barrier();                                               \
    /* p3: convert+write A(t+1)->NB (compiler's counted vmcnt drains av        \
           AND, in-order, B(t+1)); no drain-to-0 in the loop */                 \
    RDA(BUF, 6)                                                                 \
    CVTW(AWE, AWO)                                                              \
    PH_TAIL                                                                     \
    PH_MFMA(6)                                                                  \
    __builtin_amdgcn_s_barrier();                                               \
  }

    // ---- prologue: av(0)+B(0); convert A(0); B(1); counted waits ----
    AGLD(0)
    STAGEB(0, 0, 0); STAGEB(0, 1, 0); STAGEB(0, 2, 0); STAGEB(0, 3, 0);
    CVTW(awb0E, awb0O)
    STAGEB(1, 0, 1); STAGEB(1, 1, 1); STAGEB(1, 2, 1); STAGEB(1, 3, 1);
    asm volatile("s_waitcnt vmcnt(4)" ::: "memory");
    __builtin_amdgcn_sched_barrier(0);
    asm volatile("s_waitcnt lgkmcnt(0)" ::: "memory");
    __builtin_amdgcn_sched_barrier(0);
    __builtin_amdgcn_s_barrier();

    for (int t2 = 0; t2 < TK; t2 += 2) {
        TILE(t2,     0, 1, awb1E, awb1O)
        TILE(t2 + 1, 1, 0, awb0E, awb0O)
    }

    // ================= EPILOGUE: outputs + fused activation =================
    // Drain all DMA/ds traffic, then LDS is free for the act staging.
    asm volatile("s_waitcnt vmcnt(0) lgkmcnt(0)" ::: "memory");
    __builtin_amdgcn_sched_barrier(0);
    __syncthreads();

    // bias per lane's 4 nf columns (clamp dead col 1020)
    float bv[4];
#pragma unroll
    for (int nf = 0; nf < 4; ++nf) {
        int col = bn * 255 + wc * 64 + nf * 16 + (int)l15;
        bv[nf] = bias[col < NDIM ? col : NDIM - 1];
    }

    // outputs write (C/D: col=lane&15, row=(lane>>4)*4+r). Col 255 of a tile
    // duplicates neighbor's col 0 with an identical value (benign).
#pragma unroll
    for (int nf = 0; nf < 4; ++nf) {
        const int col = bn * 255 + wc * 64 + nf * 16 + (int)l15;
        if (col < NDIM) {
#pragma unroll
            for (int mf = 0; mf < 8; ++mf) {
                const int row = bm * 256 + wr * 128 + mf * 16 + ((lane >> 4) << 2);
                float* op = out + (size_t)row * NDIM + col;
#pragma unroll
                for (int r = 0; r < 4; ++r)
                    op[(size_t)r * NDIM] = acc[mf][nf][r] + bv[nf];
            }
        }
    }

    float* lf = (float*)lds_raw;                 // [128][256] f32 = 128 KiB
    const float NEG_INF = -__builtin_inff();

#pragma unroll 1
    for (int hh = 0; hh < 2; ++hh) {
        // ---- dump this half's acc (+bias) into LDS ----
        if (wr == hh) {
#pragma unroll
            for (int mf = 0; mf < 8; ++mf)
#pragma unroll
                for (int nf = 0; nf < 4; ++nf)
#pragma unroll
                    for (int r = 0; r < 4; ++r) {
                        const int rloc = mf * 16 + (int)hi * 4 + r;
                        lf[rloc * 256 + wc * 64 + nf * 16 + (int)l15] =
                            acc[mf][nf][r] + bv[nf];
                    }
        }
        __syncthreads();

        // ---- activation: wave wid owns 16 rows; 5 spans per row ----
#pragma unroll 1
        for (int rl = 0; rl < 16; ++rl) {
            const int rloc = wid * 16 + rl;                   // 0..127
            const int rowg = bm * 256 + hh * 128 + rloc;
#pragma unroll
            for (int sp = 0; sp < 5; ++sp) {
                const int cl = sp * 51 + lane;                // 0..305 (use <255)
                float o = 0.f, uu = 0.5f;
                if (lane < 51) {
                    o  = lf[rloc * 256 + cl];
                    uu = u[(size_t)rowg * NDIM + bn * 255 + cl];
                }
                const bool soft = (lane >= 1) && (lane < 51);
                const float uc = fmaxf(uu, 1e-9f);
                const float gg = -__logf(-__logf(uc));
                float z = soft ? (o + gg) * 5.0f : NEG_INF;
                float m = z;
#pragma unroll
                for (int off = 32; off; off >>= 1) m = fmaxf(m, __shfl_xor(m, off));
                float e = soft ? __expf(z - m) : 0.f;
                float s = e;
#pragma unroll
                for (int off = 32; off; off >>= 1) s += __shfl_xor(s, off);
                float res;
                if (lane == 0) {
                    const float ex = __expf(-2.0f * fabsf(o));
                    const float t  = (1.0f - ex) / (1.0f + ex);
                    res = copysignf(t, o);
                } else {
                    res = e / s;
                }
                if (lane < 51) dt[(size_t)rowg * NDIM + bn * 255 + cl] = res;
            }
        }
        __syncthreads();
    }
#undef STAGEB
#undef AGLD
#undef CVT1
#undef CVTW
#undef PH_TAIL
#undef PH_MFMA
#undef RDA
#undef RDB
#undef TILE
}

// ---------------------------------------------------------------------------
// Fallback GEMM (static 64 KiB LDS, needs Xb) if dynamic-LDS attr fails
// ---------------------------------------------------------------------------
__global__ void gemm_bf_kernel(const unsigned short* __restrict__ Xb,
                               const unsigned short* __restrict__ Wt,
                               const float* __restrict__ bias,
                               float* __restrict__ out) {
    __shared__ __align__(16) unsigned short As[128][32];
    __shared__ __align__(16) unsigned short Bs[128][32];

    const int tid  = threadIdx.x;
    const int lane = tid & 63;
    const int wid  = tid >> 6;
    const int wr   = wid >> 1;
    const int wc   = wid & 1;
    const int bn   = blockIdx.x;
    const int bm   = blockIdx.y;

    f32x4 acc[4][4];
#pragma unroll
    for (int i = 0; i < 4; ++i)
#pragma unroll
        for (int j = 0; j < 4; ++j) {
            f32x4 z = {0.f, 0.f, 0.f, 0.f};
            acc[i][j] = z;
        }

    const unsigned short* abase =
        Xb + (size_t)(bm * 128 + wid * 16 + (lane >> 2)) * KDIM + (lane & 3) * 8;
    const unsigned short* bbase =
        Wt + (size_t)(bn * 128 + wid * 16 + (lane >> 2)) * KDIM + (lane & 3) * 8;

    for (int kt = 0; kt < KDIM; kt += 32) {
#pragma unroll
        for (int j = 0; j < 2; ++j)
            __builtin_amdgcn_global_load_lds(
                (const __attribute__((address_space(1))) unsigned int*)(abase + (size_t)j * 64 * KDIM + kt),
                (__attribute__((address_space(3))) unsigned int*)(&As[j * 64 + wid * 16][0]),
                16, 0, 0);
#pragma unroll
        for (int j = 0; j < 2; ++j)
            __builtin_amdgcn_global_load_lds(
                (const __attribute__((address_space(1))) unsigned int*)(bbase + (size_t)j * 64 * KDIM + kt),
                (__attribute__((address_space(3))) unsigned int*)(&Bs[j * 64 + wid * 16][0]),
                16, 0, 0);
        __syncthreads();

        short8 af[4], bfr[4];
#pragma unroll
        for (int mi = 0; mi < 4; ++mi)
            af[mi] = *(const short8*)&As[wr * 64 + mi * 16 + (lane & 15)][(lane >> 4) * 8];
#pragma unroll
        for (int ni = 0; ni < 4; ++ni)
            bfr[ni] = *(const short8*)&Bs[wc * 64 + ni * 16 + (lane & 15)][(lane >> 4) * 8];

#pragma unroll
        for (int mi = 0; mi < 4; ++mi)
#pragma unroll
            for (int ni = 0; ni < 4; ++ni)
                acc[mi][ni] = MFMA16(af[mi], bfr[ni], acc[mi][ni]);

        __syncthreads();
    }

#pragma unroll
    for (int ni = 0; ni < 4; ++ni) {
        const int col = bn * 128 + wc * 64 + ni * 16 + (lane & 15);
        if (col < NDIM) {
            const float bv = bias[col];
#pragma unroll
            for (int mi = 0; mi < 4; ++mi) {
                const int row = bm * 128 + wr * 64 + mi * 16 + ((lane >> 4) << 2);
                float* op = out + (size_t)row * NDIM + col;
#pragma unroll
                for (int r = 0; r < 4; ++r)
                    op[(size_t)r * NDIM] = acc[mi][ni][r] + bv;
            }
        }
    }
}

// ---------------------------------------------------------------------------
// Kernel 3 (FALLBACK PATH ONLY): activation, one wave per (row, span).
// ---------------------------------------------------------------------------
__global__ void act_kernel(const float* __restrict__ outp,
                           const float* __restrict__ u,
                           float* __restrict__ dt) {
    const int lane  = threadIdx.x & 63;
    const int gwave = (blockIdx.x * 256 + threadIdx.x) >> 6;
    const int nwave = gridDim.x * 4;
    const int total = MDIM * 20;
    const float NEG_INF = -__builtin_inff();

    for (int unit = gwave; unit < total; unit += nwave) {
        const int row = unit / 20;
        const int sp  = unit - row * 20;
        const size_t base = (size_t)row * NDIM + sp * 51;

        float o = 0.f, uu = 0.5f;
        if (lane < 51) {
            o  = outp[base + lane];
            uu = u[base + lane];
        }
        const bool soft = (lane >= 1) && (lane < 51);

        const float uc = fmaxf(uu, 1e-9f);
        const float g  = -__logf(-__logf(uc));
        float z = soft ? (o + g) * 5.0f : NEG_INF;

        float m = z;
#pragma unroll
        for (int off = 32; off; off >>= 1) m = fmaxf(m, __shfl_xor(m, off));
        float e = soft ? __expf(z - m) : 0.f;
        float s = e;
#pragma unroll
        for (int off = 32; off; off >>= 1) s += __shfl_xor(s, off);

        float res;
        if (lane == 0) {
            const float ex = __expf(-2.0f * fabsf(o));
            const float t  = (1.0f - ex) / (1.0f + ex);
            res = copysignf(t, o);
        } else {
            res = e / s;
        }
        if (lane < 51) dt[base + lane] = res;
    }
}

// ---------------------------------------------------------------------------
extern "C" void kernel_launch(void* const* d_in, const int* in_sizes, int n_in,
                              void* d_out, int out_size, void* d_ws, size_t ws_size,
                              hipStream_t stream) {
    const float* x = (const float*)d_in[0];
    const float* W = (const float*)d_in[1];
    const float* b = (const float*)d_in[2];
    const float* u = (const float*)d_in[3];
    float* out = (float*)d_out;                      // outputs [M][N]
    float* dt  = out + (size_t)MDIM * NDIM;          // data_t  [M][N]
    unsigned short* Wt = (unsigned short*)d_ws;      // bf16 [NPAD][K], 4 MiB
    unsigned short* Xb = Wt + (size_t)NPAD * KDIM;   // fallback-only bf16 x

    prep_w_kernel<<<512, 256, 0, stream>>>(W, Wt);

    const hipError_t attr_ok = hipFuncSetAttribute(
        (const void*)gemm12_kernel, hipFuncAttributeMaxDynamicSharedMemorySize, 131072);
    if (attr_ok == hipSuccess) {
        gemm12_kernel<<<256, 512, 131072, stream>>>(x, Wt, b, u, out, dt);
    } else {
        prep_x_kernel<<<2048, 256, 0, stream>>>(x, Xb);
        gemm_bf_kernel<<<dim3(8, 128), 256, 0, stream>>>(Xb, Wt, b, out);
        act_kernel<<<8192, 256, 0, stream>>>(out, u, dt);
    }
}

// Round 13
// 182.951 us; speedup vs baseline: 1.5052x; 1.5052x over previous
//
#include <hip/hip_runtime.h>
#include <stdint.h>

#define MDIM 16384
#define NDIM 1020
#define KDIM 2048
#define NPAD 1024
#define TK   (KDIM / 64)   // 32 K-tiles of BK=64

typedef __attribute__((ext_vector_type(4))) float f32x4;
typedef __attribute__((ext_vector_type(8))) short short8;

#define MFMA16(a, b, c) __builtin_amdgcn_mfma_f32_16x16x32_bf16((a), (b), (c), 0, 0, 0)

// asm ds_read_b128 / ds_write_b64, register-only constraints; completion via
// manual lgkmcnt (+ sched_barrier(0) per rule 18).
template <int OFF>
static __device__ __forceinline__ short8 dsr(unsigned addr) {
    short8 r;
    asm volatile("ds_read_b128 %0, %1 offset:%2" : "=v"(r) : "v"(addr), "i"(OFF));
    return r;
}
template <int OFF>
static __device__ __forceinline__ void dsw64(unsigned addr, uint2 v) {
    asm volatile("ds_write_b64 %0, %1 offset:%2" :: "v"(addr), "v"(v), "i"(OFF));
}

// f32 -> bf16 round-to-nearest (half-up) + pack two into one u32.
__device__ __forceinline__ unsigned packbf(float lo, float hi) {
    const unsigned r0 = __float_as_uint(lo) + 0x8000u;
    const unsigned r1 = __float_as_uint(hi) + 0x8000u;
    return __builtin_amdgcn_perm(r1, r0, 0x07060302u);
}

// f32 -> bf16 RNE (prep kernels)
__device__ __forceinline__ unsigned short f2bf(float f) {
    unsigned int u = __float_as_uint(f);
    unsigned int r = (u + 0x7FFFu + ((u >> 16) & 1u)) >> 16;
    return (unsigned short)r;
}

// ---------------------------------------------------------------------------
// Kernel 1: W [K=2048][N=1020] f32 -> Wt [NPAD=1024][K=2048] bf16 (transposed)
// ---------------------------------------------------------------------------
__global__ void prep_w_kernel(const float* __restrict__ W,
                              unsigned short* __restrict__ Wt) {
    const int id = blockIdx.x * 256 + threadIdx.x;  // 512 blocks * 256
    const int n0 = (id & 255) * 4;
    const int k0 = (id >> 8) * 4;
    float a[4][4];
    if (n0 < NDIM) {
#pragma unroll
        for (int i = 0; i < 4; ++i) {
            const float* p = W + (size_t)(k0 + i) * NDIM + n0;
            a[i][0] = p[0]; a[i][1] = p[1]; a[i][2] = p[2]; a[i][3] = p[3];
        }
    } else {
#pragma unroll
        for (int i = 0; i < 4; ++i)
#pragma unroll
            for (int j = 0; j < 4; ++j) a[i][j] = 0.f;
    }
#pragma unroll
    for (int j = 0; j < 4; ++j) {
        uint2 p;
        p.x = (unsigned)f2bf(a[0][j]) | ((unsigned)f2bf(a[1][j]) << 16);
        p.y = (unsigned)f2bf(a[2][j]) | ((unsigned)f2bf(a[3][j]) << 16);
        *(uint2*)(Wt + (size_t)(n0 + j) * KDIM + k0) = p;
    }
}

// ---------------------------------------------------------------------------
// Kernel 1b (FALLBACK PATH ONLY): x f32 -> Xb bf16
// ---------------------------------------------------------------------------
__global__ void prep_x_kernel(const float* __restrict__ x,
                              unsigned short* __restrict__ Xb) {
    const size_t total = (size_t)MDIM * KDIM;
    const size_t stride = (size_t)gridDim.x * 256 * 8;
    for (size_t i = ((size_t)blockIdx.x * 256 + threadIdx.x) * 8; i < total; i += stride) {
        const float4 v0 = *(const float4*)(x + i);
        const float4 v1 = *(const float4*)(x + i + 4);
        uint4 p;
        p.x = (unsigned)f2bf(v0.x) | ((unsigned)f2bf(v0.y) << 16);
        p.y = (unsigned)f2bf(v0.z) | ((unsigned)f2bf(v0.w) << 16);
        p.z = (unsigned)f2bf(v1.x) | ((unsigned)f2bf(v1.y) << 16);
        p.w = (unsigned)f2bf(v1.z) | ((unsigned)f2bf(v1.w) << 16);
        *(uint4*)(Xb + i) = p;
    }
}

// ---------------------------------------------------------------------------
// Kernel 2 (R13 = R10 verbatim, session best): fused-convert 256x256 GEMM,
// BK=64, 8 waves. A staged directly from f32 x (float4 -> packbf -> swizzled
// ds_write_b64, E/O XOR bases); B via global_load_lds with pre-swizzled
// source. R3/R4 phase schedule. Fused act (R12) rejected: -120us from TLP
// collapse. Direct-B-reg (R8) rejected: uncoalesced. Counted-wait variants
// (R4/R5/R6/R11) all null -> this is the verified best of the design space.
// ---------------------------------------------------------------------------
extern "C" __global__ __launch_bounds__(512, 2) void gemm10_kernel(
    const float* __restrict__ x,
    const unsigned short* __restrict__ Wt,
    const float* __restrict__ bias,
    float* __restrict__ out) {
    extern __shared__ unsigned short lds_raw[];  // 2 bufs x (A 32KB + B 32KB)

    const int tid  = threadIdx.x;
    const int lane = tid & 63;
    const int wid  = tid >> 6;   // 0..7
    const int wr   = wid >> 2;   // 0..1 (M)
    const int wc   = wid & 3;    // 0..3 (N)

    // XCD-aware swizzle: 256 blocks, 8 XCDs, 32 consecutive per XCD.
    const int bid = blockIdx.x;
    const int swz = (bid & 7) * 32 + (bid >> 3);
    const int bm  = swz >> 2;    // 0..63
    const int bn  = swz & 3;     // 0..3

    // B staging source (rule 21 pre-swizzle; verified R3/R4)
    const int srow = wid * 8 + (lane >> 3);
    const int scb  = ((lane & 7) ^ (lane >> 3)) * 8;
    const unsigned short* bS = Wt + (size_t)(bn * 256 + srow) * KDIM + scb;

#define STAGEB(BUFI, STRIPE, S) do {                                             \
    const unsigned short* sp_ =                                                  \
        bS + (size_t)((STRIPE) * 64) * KDIM + (size_t)(((S) & 31) * 64);         \
    __builtin_amdgcn_global_load_lds(                                            \
        (const __attribute__((address_space(1))) unsigned int*)sp_,              \
        (__attribute__((address_space(3))) unsigned int*)(lds_raw +              \
            (BUFI) * 32768 + 16384 + ((STRIPE) * 64 + wid * 8) * 64),            \
        16, 0, 0);                                                               \
} while (0)

    // A direct-f32 source: lane covers row r = wid*32 + i*4 + h (i=0..7),
    // k-group g = lane&15 (float4 at k=g*4) -- fully coalesced.
    const int h = lane >> 4, g = lane & 15;
    const float* aF = x + (size_t)(bm * 256 + wid * 32 + h) * KDIM + g * 4;

    // A LDS write: byte = buf*65536 + r*128 + ((g>>1 ^ (r&7))<<4) + (g&1)*8
    // r&7 = 4*(i&1)+h -> base E (i even); O = E ^ 0x40 (XOR! R9's carry bug).
    const unsigned ldsbase =
        (unsigned)(uintptr_t)(__attribute__((address_space(3))) unsigned short*)lds_raw;
    const unsigned awbE =
        ldsbase + (unsigned)(wid * 32 + h) * 128 +
        ((unsigned)((g >> 1) ^ h) << 4) + (unsigned)(g & 1) * 8;
    const unsigned awbO  = awbE ^ 0x40u;
    const unsigned awb0E = awbE,           awb0O = awbO;
    const unsigned awb1E = awbE + 65536u,  awb1O = awbO + 65536u;

    float4 av[8];
#define AGLD(T) {                                                     \
    const float* ap_ = aF + (size_t)(((T) & 31) * 64);                \
    av[0] = *(const float4*)(ap_);                                    \
    av[1] = *(const float4*)(ap_ + 4 * KDIM);                         \
    av[2] = *(const float4*)(ap_ + 8 * KDIM);                         \
    av[3] = *(const float4*)(ap_ + 12 * KDIM);                        \
    av[4] = *(const float4*)(ap_ + 16 * KDIM);                        \
    av[5] = *(const float4*)(ap_ + 20 * KDIM);                        \
    av[6] = *(const float4*)(ap_ + 24 * KDIM);                        \
    av[7] = *(const float4*)(ap_ + 28 * KDIM);                        \
}
#define CVT1(AWE, AWO, I)                                             \
    { uint2 v_;                                                       \
      v_.x = packbf(av[I].x, av[I].y);                                \
      v_.y = packbf(av[I].z, av[I].w);                                \
      dsw64<(I) * 512>(((I) & 1) ? (AWO) : (AWE), v_); }
#define CVTW(AWE, AWO)                                                \
    CVT1(AWE, AWO, 0) CVT1(AWE, AWO, 1) CVT1(AWE, AWO, 2)             \
    CVT1(AWE, AWO, 3) CVT1(AWE, AWO, 4) CVT1(AWE, AWO, 5)             \
    CVT1(AWE, AWO, 6) CVT1(AWE, AWO, 7)

    // A/B LDS read addressing (verified R3/R4)
    const unsigned l15 = lane & 15, hi = lane >> 4, l7 = lane & 7;
    const unsigned c0 = (unsigned)((0 * 4 + hi) ^ l7) << 4;
    const unsigned c1 = (unsigned)((1 * 4 + hi) ^ l7) << 4;
    const unsigned pbA = ldsbase + (unsigned)(wr * 128 + l15) * 128;
    const unsigned pbB = ldsbase + 32768u + (unsigned)(wc * 64 + l15) * 128;
    const unsigned aA0_0 = pbA + c0,          aA0_1 = pbA + c1;
    const unsigned aA1_0 = pbA + 65536u + c0, aA1_1 = pbA + 65536u + c1;
    const unsigned bB0_0 = pbB + c0,          bB0_1 = pbB + c1;
    const unsigned bB1_0 = pbB + 65536u + c0, bB1_1 = pbB + 65536u + c1;

    f32x4 acc[8][4];
#pragma unroll
    for (int i = 0; i < 8; ++i)
#pragma unroll
        for (int j = 0; j < 4; ++j) {
            f32x4 z = {0.f, 0.f, 0.f, 0.f};
            acc[i][j] = z;
        }

#define PH_TAIL                                                       \
    __builtin_amdgcn_s_barrier();                                     \
    asm volatile("s_waitcnt lgkmcnt(0)" ::: "memory");                \
    __builtin_amdgcn_sched_barrier(0);                                \
    __builtin_amdgcn_s_setprio(1);

#define PH_MFMA(MF0)                                                  \
    _Pragma("unroll")                                                 \
    for (int nf = 0; nf < 4; ++nf) {                                  \
        acc[MF0][nf]     = MFMA16(af0[0], bfv[nf][0], acc[MF0][nf]);      \
        acc[MF0][nf]     = MFMA16(af0[1], bfv[nf][1], acc[MF0][nf]);      \
        acc[MF0 + 1][nf] = MFMA16(af1[0], bfv[nf][0], acc[MF0 + 1][nf]);  \
        acc[MF0 + 1][nf] = MFMA16(af1[1], bfv[nf][1], acc[MF0 + 1][nf]);  \
    }                                                                 \
    __builtin_amdgcn_sched_barrier(0);                                \
    __builtin_amdgcn_s_setprio(0);

#define RDA(BUF, MF0)                                                 \
    af0[0] = dsr<(MF0) * 2048>(aA##BUF##_0);                          \
    af0[1] = dsr<(MF0) * 2048>(aA##BUF##_1);                          \
    af1[0] = dsr<(MF0) * 2048 + 2048>(aA##BUF##_0);                   \
    af1[1] = dsr<(MF0) * 2048 + 2048>(aA##BUF##_1);

#define RDB(BUF, NF)                                                  \
    bfv[NF][0] = dsr<(NF) * 2048>(bB##BUF##_0);                       \
    bfv[NF][1] = dsr<(NF) * 2048>(bB##BUF##_1);

#define TILE(T, BUF, NB, AWE, AWO)                                              \
  {                                                                             \
    short8 bfv[4][2];                                                           \
    short8 af0[2], af1[2];                                                      \
    /* ---- phase 0: reads B(t)+A(t)mf01; issue A-gloads (t+1) ---- */          \
    RDB(BUF, 0) RDB(BUF, 1) RDB(BUF, 2) RDB(BUF, 3)                             \
    RDA(BUF, 0)                                                                 \
    AGLD((T) + 1)                                                               \
    PH_TAIL                                                                     \
    PH_MFMA(0)                                                                  \
    __builtin_amdgcn_s_barrier();                                               \
    /* ---- phase 1 ---- */                                                     \
    RDA(BUF, 2)                                                                 \
    STAGEB(NB, 0, (T) + 1); STAGEB(NB, 1, (T) + 1);                             \
    PH_TAIL                                                                     \
    PH_MFMA(2)                                                                  \
    __builtin_amdgcn_s_barrier();                                               \
    /* ---- phase 2 ---- */                                                     \
    RDA(BUF, 4)                                                                 \
    STAGEB(NB, 2, (T) + 1); STAGEB(NB, 3, (T) + 1);                             \
    PH_TAIL                                                                     \
    PH_MFMA(4)                                                                  \
    __builtin_amdgcn_s_barrier();                                               \
    /* ---- phase 3: convert+write A(t+1) -> nb; drain VM at tile end ---- */   \
    RDA(BUF, 6)                                                                 \
    CVTW(AWE, AWO)                                                              \
    PH_TAIL                                                                     \
    PH_MFMA(6)                                                                  \
    asm volatile("s_waitcnt vmcnt(0)" ::: "memory");                            \
    __builtin_amdgcn_sched_barrier(0);                                          \
    __builtin_amdgcn_s_barrier();                                               \
  }

    // ---- prologue: tile0 -> buf0 (A via reg-convert, B via DMA) ----
    AGLD(0)
    STAGEB(0, 0, 0); STAGEB(0, 1, 0); STAGEB(0, 2, 0); STAGEB(0, 3, 0);
    CVTW(awb0E, awb0O)
    asm volatile("s_waitcnt lgkmcnt(0)" ::: "memory");
    __builtin_amdgcn_sched_barrier(0);
    asm volatile("s_waitcnt vmcnt(0)" ::: "memory");
    __builtin_amdgcn_sched_barrier(0);
    __builtin_amdgcn_s_barrier();

    for (int t2 = 0; t2 < TK; t2 += 2) {
        TILE(t2,     0, 1, awb1E, awb1O)
        TILE(t2 + 1, 1, 0, awb0E, awb0O)
    }

    // ---- epilogue: bias + store (C/D: col=lane&15, row=(lane>>4)*4+r) ----
#pragma unroll
    for (int nf = 0; nf < 4; ++nf) {
        const int col = bn * 256 + wc * 64 + nf * 16 + (lane & 15);
        if (col < NDIM) {
            const float bv = bias[col];
#pragma unroll
            for (int mf = 0; mf < 8; ++mf) {
                const int row = bm * 256 + wr * 128 + mf * 16 + ((lane >> 4) << 2);
                float* op = out + (size_t)row * NDIM + col;
#pragma unroll
                for (int r = 0; r < 4; ++r)
                    op[(size_t)r * NDIM] = acc[mf][nf][r] + bv;
            }
        }
    }
#undef STAGEB
#undef AGLD
#undef CVT1
#undef CVTW
#undef PH_TAIL
#undef PH_MFMA
#undef RDA
#undef RDB
#undef TILE
}

// ---------------------------------------------------------------------------
// Fallback GEMM (static 64 KiB LDS, needs Xb) if dynamic-LDS attr fails
// ---------------------------------------------------------------------------
__global__ void gemm_bf_kernel(const unsigned short* __restrict__ Xb,
                               const unsigned short* __restrict__ Wt,
                               const float* __restrict__ bias,
                               float* __restrict__ out) {
    __shared__ __align__(16) unsigned short As[128][32];
    __shared__ __align__(16) unsigned short Bs[128][32];

    const int tid  = threadIdx.x;
    const int lane = tid & 63;
    const int wid  = tid >> 6;
    const int wr   = wid >> 1;
    const int wc   = wid & 1;
    const int bn   = blockIdx.x;
    const int bm   = blockIdx.y;

    f32x4 acc[4][4];
#pragma unroll
    for (int i = 0; i < 4; ++i)
#pragma unroll
        for (int j = 0; j < 4; ++j) {
            f32x4 z = {0.f, 0.f, 0.f, 0.f};
            acc[i][j] = z;
        }

    const unsigned short* abase =
        Xb + (size_t)(bm * 128 + wid * 16 + (lane >> 2)) * KDIM + (lane & 3) * 8;
    const unsigned short* bbase =
        Wt + (size_t)(bn * 128 + wid * 16 + (lane >> 2)) * KDIM + (lane & 3) * 8;

    for (int kt = 0; kt < KDIM; kt += 32) {
#pragma unroll
        for (int j = 0; j < 2; ++j)
            __builtin_amdgcn_global_load_lds(
                (const __attribute__((address_space(1))) unsigned int*)(abase + (size_t)j * 64 * KDIM + kt),
                (__attribute__((address_space(3))) unsigned int*)(&As[j * 64 + wid * 16][0]),
                16, 0, 0);
#pragma unroll
        for (int j = 0; j < 2; ++j)
            __builtin_amdgcn_global_load_lds(
                (const __attribute__((address_space(1))) unsigned int*)(bbase + (size_t)j * 64 * KDIM + kt),
                (__attribute__((address_space(3))) unsigned int*)(&Bs[j * 64 + wid * 16][0]),
                16, 0, 0);
        __syncthreads();

        short8 af[4], bfr[4];
#pragma unroll
        for (int mi = 0; mi < 4; ++mi)
            af[mi] = *(const short8*)&As[wr * 64 + mi * 16 + (lane & 15)][(lane >> 4) * 8];
#pragma unroll
        for (int ni = 0; ni < 4; ++ni)
            bfr[ni] = *(const short8*)&Bs[wc * 64 + ni * 16 + (lane & 15)][(lane >> 4) * 8];

#pragma unroll
        for (int mi = 0; mi < 4; ++mi)
#pragma unroll
            for (int ni = 0; ni < 4; ++ni)
                acc[mi][ni] = MFMA16(af[mi], bfr[ni], acc[mi][ni]);

        __syncthreads();
    }

#pragma unroll
    for (int ni = 0; ni < 4; ++ni) {
        const int col = bn * 128 + wc * 64 + ni * 16 + (lane & 15);
        if (col < NDIM) {
            const float bv = bias[col];
#pragma unroll
            for (int mi = 0; mi < 4; ++mi) {
                const int row = bm * 128 + wr * 64 + mi * 16 + ((lane >> 4) << 2);
                float* op = out + (size_t)row * NDIM + col;
#pragma unroll
                for (int r = 0; r < 4; ++r)
                    op[(size_t)r * NDIM] = acc[mi][ni][r] + bv;
            }
        }
    }
}

// ---------------------------------------------------------------------------
// Kernel 3: activation. One wave per (row, span of 51 cols). 32768 waves ->
// latency fully hidden by TLP (R12's fusion proved this must stay separate).
// ---------------------------------------------------------------------------
__global__ void act_kernel(const float* __restrict__ outp,
                           const float* __restrict__ u,
                           float* __restrict__ dt) {
    const int lane  = threadIdx.x & 63;
    const int gwave = (blockIdx.x * 256 + threadIdx.x) >> 6;
    const int nwave = gridDim.x * 4;
    const int total = MDIM * 20;
    const float NEG_INF = -__builtin_inff();

    for (int unit = gwave; unit < total; unit += nwave) {
        const int row = unit / 20;
        const int sp  = unit - row * 20;
        const size_t base = (size_t)row * NDIM + sp * 51;

        float o = 0.f, uu = 0.5f;
        if (lane < 51) {
            o  = outp[base + lane];
            uu = u[base + lane];
        }
        const bool soft = (lane >= 1) && (lane < 51);

        const float uc = fmaxf(uu, 1e-9f);
        const float g  = -__logf(-__logf(uc));
        float z = soft ? (o + g) * 5.0f : NEG_INF;

        float m = z;
#pragma unroll
        for (int off = 32; off; off >>= 1) m = fmaxf(m, __shfl_xor(m, off));
        float e = soft ? __expf(z - m) : 0.f;
        float s = e;
#pragma unroll
        for (int off = 32; off; off >>= 1) s += __shfl_xor(s, off);

        float res;
        if (lane == 0) {
            const float ex = __expf(-2.0f * fabsf(o));
            const float t  = (1.0f - ex) / (1.0f + ex);
            res = copysignf(t, o);
        } else {
            res = e / s;
        }
        if (lane < 51) dt[base + lane] = res;
    }
}

// ---------------------------------------------------------------------------
extern "C" void kernel_launch(void* const* d_in, const int* in_sizes, int n_in,
                              void* d_out, int out_size, void* d_ws, size_t ws_size,
                              hipStream_t stream) {
    const float* x = (const float*)d_in[0];
    const float* W = (const float*)d_in[1];
    const float* b = (const float*)d_in[2];
    const float* u = (const float*)d_in[3];
    float* out = (float*)d_out;                      // outputs [M][N]
    float* dt  = out + (size_t)MDIM * NDIM;          // data_t  [M][N]
    unsigned short* Wt = (unsigned short*)d_ws;      // bf16 [NPAD][K], 4 MiB
    unsigned short* Xb = Wt + (size_t)NPAD * KDIM;   // fallback-only bf16 x

    prep_w_kernel<<<512, 256, 0, stream>>>(W, Wt);

    const hipError_t attr_ok = hipFuncSetAttribute(
        (const void*)gemm10_kernel, hipFuncAttributeMaxDynamicSharedMemorySize, 131072);
    if (attr_ok == hipSuccess) {
        gemm10_kernel<<<256, 512, 131072, stream>>>(x, Wt, b, out);
    } else {
        prep_x_kernel<<<2048, 256, 0, stream>>>(x, Xb);
        gemm_bf_kernel<<<dim3(8, 128), 256, 0, stream>>>(Xb, Wt, b, out);
    }

    act_kernel<<<8192, 256, 0, stream>>>(out, u, dt);
}